// Round 1
// baseline (177.622 us; speedup 1.0000x reference)
//
#include <hip/hip_runtime.h>
#include <hip/hip_bf16.h>
#include <math.h>

#define B_DIM 8
#define T_DIM 2048
#define D_DIM 1024
#define H_DIM 64
#define SCALE 0.125f

typedef __attribute__((ext_vector_type(8))) short bf16x8;
typedef __attribute__((ext_vector_type(4))) float f32x4;

__device__ __forceinline__ f32x4 mfma16(bf16x8 a, bf16x8 b, f32x4 c) {
    return __builtin_amdgcn_mfma_f32_16x16x32_bf16(a, b, c, 0, 0, 0);
}

__device__ __forceinline__ float rcp_fast(float x) {
    float r;
    asm volatile("v_rcp_f32 %0, %1" : "=v"(r) : "v"(x));
    return r;
}

__device__ __forceinline__ short f2bf(float f) {
    __hip_bfloat16 h = __float2bfloat16(f);
    return *reinterpret_cast<short*>(&h);
}

__device__ __forceinline__ float bf2f(short s) {
    return __uint_as_float(((unsigned int)(unsigned short)s) << 16);
}

__device__ __forceinline__ unsigned pk2(float a, float b) {
    __hip_bfloat162 h = __float22bfloat162_rn(make_float2(a, b));
    return *reinterpret_cast<unsigned*>(&h);
}

__device__ __forceinline__ void cvt4(float4 v, short* dst) {
    __hip_bfloat162 p0 = __float22bfloat162_rn(make_float2(v.x, v.y));
    __hip_bfloat162 p1 = __float22bfloat162_rn(make_float2(v.z, v.w));
    uint2 u;
    u.x = *reinterpret_cast<unsigned int*>(&p0);
    u.y = *reinterpret_cast<unsigned int*>(&p1);
    *reinterpret_cast<uint2*>(dst) = u;  // dst 8B-aligned
}

// ---------------------------------------------------------------------------
// prep: transpose-convert W (fp32 [k][h]) -> wt bf16 [m][h][k]. 48 blocks.
// ---------------------------------------------------------------------------
__global__ __launch_bounds__(256) void prep_kernel(
    const float* __restrict__ Wq, const float* __restrict__ Wk,
    const float* __restrict__ Wv, short* __restrict__ wt)
{
    const int blk = blockIdx.x;
    const int tid = threadIdx.x;
    const int m = blk >> 4;
    const int ks = (blk & 15) << 6;
    const float* W = (m == 0) ? Wq : (m == 1) ? Wk : Wv;
    __shared__ float tile[64][68];
#pragma unroll
    for (int t = 0; t < 4; t++) {
        int fi = tid + t * 256;
        int k = fi >> 4, h4 = (fi & 15) << 2;
        *(float4*)&tile[k][h4] = *(const float4*)&W[(size_t)(ks + k) * H_DIM + h4];
    }
    __syncthreads();
    const int h = tid >> 2, seg = (tid & 3) << 4;
    __align__(16) short tmp[16];
#pragma unroll
    for (int kk = 0; kk < 16; kk++) tmp[kk] = f2bf(tile[seg + kk][h]);
    short* dst = wt + ((size_t)m * H_DIM + h) * D_DIM + ks + seg;
    *(bf16x8*)dst = *(bf16x8*)tmp;
    *(bf16x8*)(dst + 8) = *(bf16x8*)(tmp + 8);
}

// ---------------------------------------------------------------------------
// proj: grid 512 (32 rows each), block 256. q|k|v (192 cols) per row tile,
// double-buffered LDS (1 barrier/iter) + global->reg prefetch.
// Outputs: qb,kb bf16 [t][h]; vt bf16 [b][h][t].
// ---------------------------------------------------------------------------
__global__ __launch_bounds__(256) void proj_kernel(
    const float* __restrict__ x, const short* __restrict__ wt,
    short* __restrict__ qb, short* __restrict__ kb, short* __restrict__ vt)
{
    __shared__ short xs[2][32][72];
    __shared__ short wsb[2][192][72];
    __shared__ short ot[32][200];

    const int tid = threadIdx.x;
    const int wv = tid >> 6;
    const int lane = tid & 63;
    const int l15 = lane & 15;
    const int quad = lane >> 4;
    const int t0 = blockIdx.x * 32;
    const int r0 = (wv & 1) * 16;
    const int c0 = (wv >> 1) * 96;

    f32x4 acc[6];
#pragma unroll
    for (int c = 0; c < 6; c++) acc[c] = (f32x4){0.f, 0.f, 0.f, 0.f};

    float4 xr[2];
    bf16x8 wr[6];
    auto load_tile = [&](int k0) {
#pragma unroll
        for (int t = 0; t < 2; t++) {
            int fi = tid + t * 256;
            int r = fi >> 4, c4 = (fi & 15) << 2;
            xr[t] = *(const float4*)&x[(size_t)(t0 + r) * D_DIM + k0 + c4];
        }
#pragma unroll
        for (int t = 0; t < 6; t++) {
            int fi = tid + t * 256;
            int hh = fi >> 3, sg = (fi & 7) << 3;
            wr[t] = *(const bf16x8*)&wt[(size_t)hh * D_DIM + k0 + sg];
        }
    };
    auto store_tile = [&](int buf) {
#pragma unroll
        for (int t = 0; t < 2; t++) {
            int fi = tid + t * 256;
            int r = fi >> 4, c4 = (fi & 15) << 2;
            cvt4(xr[t], &xs[buf][r][c4]);
        }
#pragma unroll
        for (int t = 0; t < 6; t++) {
            int fi = tid + t * 256;
            int hh = fi >> 3, sg = (fi & 7) << 3;
            *(bf16x8*)&wsb[buf][hh][sg] = wr[t];
        }
    };

    load_tile(0);
    store_tile(0);
    __syncthreads();

    for (int it = 0; it < 16; ++it) {
        const int cur = it & 1;
        if (it < 15) load_tile((it + 1) * 64);
#pragma unroll
        for (int ks = 0; ks < 2; ks++) {
            bf16x8 xa = *(const bf16x8*)&xs[cur][r0 + l15][ks * 32 + quad * 8];
#pragma unroll
            for (int ct = 0; ct < 6; ct++) {
                bf16x8 wb = *(const bf16x8*)&wsb[cur][c0 + ct * 16 + l15][ks * 32 + quad * 8];
                acc[ct] = mfma16(xa, wb, acc[ct]);
            }
        }
        if (it < 15) store_tile(cur ^ 1);
        __syncthreads();
    }

    // epilogue: C-frags -> LDS bf16 tile
#pragma unroll
    for (int ct = 0; ct < 6; ct++)
#pragma unroll
        for (int r = 0; r < 4; r++)
            ot[r0 + quad * 4 + r][c0 + ct * 16 + l15] = f2bf(acc[ct][r]);
    __syncthreads();
#pragma unroll
    for (int t = 0; t < 2; t++) {
        int fi = tid + t * 256;
        int row = fi >> 4, sg = fi & 15;
        bf16x8 v = *(const bf16x8*)&ot[row][sg * 8];
        short* dst = (sg < 8)
            ? &qb[(size_t)(t0 + row) * H_DIM + sg * 8]
            : &kb[(size_t)(t0 + row) * H_DIM + (sg - 8) * 8];
        *(bf16x8*)dst = v;
    }
    {
        const int h = tid >> 2, ts = (tid & 3) << 3;
        const int bb = t0 >> 11;
        const int tloc = (t0 & 2047) + ts;
        __align__(16) short tmp[8];
#pragma unroll
        for (int i = 0; i < 8; i++) tmp[i] = ot[ts + i][128 + h];
        *(bf16x8*)&vt[((size_t)bb * H_DIM + h) * T_DIM + tloc] = *(bf16x8*)tmp;
    }
}

// ---------------------------------------------------------------------------
// stats: Z[k] = sum_{q>=k} exp(s*scale), then vt[:,k] *= 1/Z[k] in-place.
// grid 512 (1-D): batch = bx & 7 so all blocks of a batch share an XCD
// (round-robin linear-ID mapping) -> K/Q stay in that XCD's 4 MB L2.
// Block = k-strip pair {sa, 127-sa}; K stationary, Q ping-pong prefetch.
// ---------------------------------------------------------------------------
__global__ __launch_bounds__(256) void stats_kernel(
    const short* __restrict__ qb, const short* __restrict__ kb,
    short* __restrict__ vt)
{
    __shared__ float zred[4][2][16];
    __shared__ float zfin[2][16];
    const int tid = threadIdx.x;
    const int wv = tid >> 6;
    const int lane = tid & 63;
    const int l15 = lane & 15;
    const int quad = lane >> 4;
    const int b = blockIdx.x & 7;          // XCD-pinned batch
    const int sa = blockIdx.x >> 3;        // 0..63
    const int sb = 127 - sa;
    const int Ta = 128 - sa;

    const short* qB_ = qb + (size_t)b * T_DIM * H_DIM;
    const short* kB_ = kb + (size_t)b * T_DIM * H_DIM;

    bf16x8 ka[2][2];
    {
        const short* kp = &kB_[(sa * 16 + l15) * H_DIM + quad * 8];
        ka[0][0] = *(const bf16x8*)kp;
        ka[0][1] = *(const bf16x8*)(kp + 32);
        const short* kp2 = &kB_[(sb * 16 + l15) * H_DIM + quad * 8];
        ka[1][0] = *(const bf16x8*)kp2;
        ka[1][1] = *(const bf16x8*)(kp2 + 32);
    }

    float acc[2][4];
#pragma unroll
    for (int s = 0; s < 2; s++)
#pragma unroll
        for (int r = 0; r < 4; r++) acc[s][r] = 0.f;

    const int v0 = (wv * 129) >> 2;
    const int v1 = ((wv + 1) * 129) >> 2;

#pragma unroll
    for (int seg = 0; seg < 2; ++seg) {
        const int strip = seg ? sb : sa;
        const int base = seg ? Ta : 0;
        const int lo = seg ? max(v0, Ta) : v0;
        const int hi = seg ? v1 : min(v1, Ta);
        const bf16x8 a0 = ka[seg][0], a1 = ka[seg][1];

        bf16x8 qA0, qA1, qB0, qB1;
        auto loadQ = [&](int v, bf16x8& r0, bf16x8& r1) {
            int qt = strip + (v - base);
            const short* qp = &qB_[(qt * 16 + l15) * H_DIM + quad * 8];
            r0 = *(const bf16x8*)qp;
            r1 = *(const bf16x8*)(qp + 32);
        };
        auto comp = [&](int v, bf16x8 b0, bf16x8 b1) {
            int qt = strip + (v - base);
            f32x4 s = mfma16(a0, b0, (f32x4){0.f, 0.f, 0.f, 0.f});
            s = mfma16(a1, b1, s);
            const bool diag = (qt == strip);
#pragma unroll
            for (int r = 0; r < 4; ++r) {
                float e = __expf(s[r] * SCALE);
                if (diag && (quad * 4 + r) > l15) e = 0.f;
                acc[seg][r] += e;
            }
        };

        int v = lo;
        if (v < hi) loadQ(v, qA0, qA1);
        while (v < hi) {
            if (v + 1 < hi) loadQ(v + 1, qB0, qB1);
            comp(v, qA0, qA1);
            ++v;
            if (v >= hi) break;
            if (v + 1 < hi) loadQ(v + 1, qA0, qA1);
            comp(v, qB0, qB1);
            ++v;
        }
    }

    // butterfly over l15 (sum across 16 q-cols), then LDS combine of 4 waves
#pragma unroll
    for (int seg = 0; seg < 2; ++seg)
#pragma unroll
        for (int r = 0; r < 4; ++r) {
            float z = acc[seg][r];
            z += __shfl_xor(z, 1);
            z += __shfl_xor(z, 2);
            z += __shfl_xor(z, 4);
            z += __shfl_xor(z, 8);
            acc[seg][r] = z;
        }
    if (l15 == 0) {
#pragma unroll
        for (int seg = 0; seg < 2; ++seg)
#pragma unroll
            for (int r = 0; r < 4; ++r)
                zred[wv][seg][quad * 4 + r] = acc[seg][r];
    }
    __syncthreads();
    if (tid < 32) {
        int seg = tid >> 4, col = tid & 15;
        float z = zred[0][seg][col] + zred[1][seg][col] +
                  zred[2][seg][col] + zred[3][seg][col];
        zfin[seg][col] = rcp_fast(z);
    }
    __syncthreads();

    // scale vt columns of both strips by 1/Z: 2 strips x 64 h x 16 t
    {
        const int seg = tid >> 7;             // 0/1
        const int rem = tid & 127;
        const int h = rem >> 1;               // 0..63
        const int c8 = (rem & 1) * 8;         // 0 or 8
        const int strip = seg ? sb : sa;
        short* vp = vt + ((size_t)b * H_DIM + h) * T_DIM + strip * 16 + c8;
        bf16x8 vv = *(bf16x8*)vp;
        __align__(16) short tmp[8];
#pragma unroll
        for (int i = 0; i < 8; i++)
            tmp[i] = f2bf(bf2f(vv[i]) * zfin[seg][c8 + i]);
        *(bf16x8*)vp = *(bf16x8*)tmp;
    }
}

// ---------------------------------------------------------------------------
// out: grid 512 (1-D): batch = bx & 7 (XCD-pinned -> K/V L2-resident).
// Block = strip pair {s, 127-s} (16 q-rows each, uniform work); waves
// quarter the k-range. Ping-pong register prefetch of K/V. V pre-scaled by
// 1/Z, so P = exp(s*scale) directly.
//
// Swapped-operand QK^T: s = mfma(K, Q) puts q in lanes (l15) and k in
// (quad,reg) -- exactly the PV A-operand row layout. P never touches LDS:
// 4 packed cvts build the PV A-frag in-register. The A-slot k-permutation
// (slot quad*8+j carries k = (j>>2)*16 + quad*4 + (j&3)) is absorbed into
// the V load addressing: two 8B loads at +quad*4 and +16+quad*4 per frag.
// Partial O combined in LDS (osum) as before.
// ---------------------------------------------------------------------------
__global__ __launch_bounds__(256) void out_kernel(
    const short* __restrict__ qb, const short* __restrict__ kb,
    const short* __restrict__ vt, float* __restrict__ out)
{
    __shared__ float osum[4][2][16][68];   // 34.8 KB

    const int tid = threadIdx.x;
    const int wv = tid >> 6;
    const int lane = tid & 63;
    const int l15 = lane & 15;
    const int quad = lane >> 4;
    const int b = blockIdx.x & 7;          // XCD-pinned batch
    const int sA = blockIdx.x >> 3;        // 0..63

    const short* qB_ = qb + (size_t)b * T_DIM * H_DIM;
    const short* kB_ = kb + (size_t)b * T_DIM * H_DIM;
    const short* vB_ = vt + (size_t)b * H_DIM * T_DIM;

#pragma unroll
    for (int half = 0; half < 2; half++) {
        const int s = half ? (127 - sA) : sA;
        const int q0 = s * 16;
        const int Ts = (s >> 1) + 1;
        const int lo = (wv * Ts) >> 2;
        const int hi = ((wv + 1) * Ts) >> 2;

        const bf16x8 qa0 = *(const bf16x8*)&qB_[(q0 + l15) * H_DIM + quad * 8];
        const bf16x8 qa1 = *(const bf16x8*)&qB_[(q0 + l15) * H_DIM + 32 + quad * 8];

        f32x4 o0 = {0.f,0.f,0.f,0.f}, o1 = {0.f,0.f,0.f,0.f};
        f32x4 o2 = {0.f,0.f,0.f,0.f}, o3 = {0.f,0.f,0.f,0.f};

        bf16x8 krA[4], vrA[4], krB[4], vrB[4];

        auto loadT = [&](int kt, bf16x8* kr, bf16x8* vr) {
            const short* kp = &kB_[(kt * 32 + l15) * H_DIM + quad * 8];
            kr[0] = *(const bf16x8*)kp;
            kr[1] = *(const bf16x8*)(kp + 32);
            kr[2] = *(const bf16x8*)(kp + 16 * H_DIM);
            kr[3] = *(const bf16x8*)(kp + 16 * H_DIM + 32);
            // V with slot-permuted k: slots quad*8+{0..3} <- t = kt*32+quad*4+{0..3}
            //                         slots quad*8+{4..7} <- t = kt*32+16+quad*4+{0..3}
            const short* vp = &vB_[(size_t)l15 * T_DIM + kt * 32 + quad * 4];
#pragma unroll
            for (int jh = 0; jh < 4; jh++) {
                uint2 vlo = *(const uint2*)(vp + (size_t)jh * 16 * T_DIM);
                uint2 vhi = *(const uint2*)(vp + (size_t)jh * 16 * T_DIM + 16);
                uint4 all = make_uint4(vlo.x, vlo.y, vhi.x, vhi.y);
                vr[jh] = *reinterpret_cast<bf16x8*>(&all);
            }
        };
        auto compT = [&](int kt, bf16x8* kr, bf16x8* vr) {
            __builtin_amdgcn_s_setprio(1);
            f32x4 z4 = {0.f,0.f,0.f,0.f};
            // swapped: A = K rows (k in quad/reg), B = Q rows (q in l15)
            f32x4 s0 = mfma16(kr[0], qa0, z4);
            s0 = mfma16(kr[1], qa1, s0);
            f32x4 s1 = mfma16(kr[2], qa0, z4);
            s1 = mfma16(kr[3], qa1, s1);
            const bool fullT = (kt * 32 + 31) <= q0;
            const int kg = kt * 32 + quad * 4;   // k of s0[r=0] for this lane
            const int qg = q0 + l15;             // q for this lane
            float e0[4], e1[4];
#pragma unroll
            for (int r = 0; r < 4; r++) {
                float a = __expf(s0[r] * SCALE);
                float c = __expf(s1[r] * SCALE);
                if (!fullT) {
                    if (kg + r > qg) a = 0.f;
                    if (kg + 16 + r > qg) c = 0.f;
                }
                e0[r] = a; e1[r] = c;
            }
            bf16x8 pa;
            unsigned* pu = reinterpret_cast<unsigned*>(&pa);
            pu[0] = pk2(e0[0], e0[1]);
            pu[1] = pk2(e0[2], e0[3]);
            pu[2] = pk2(e1[0], e1[1]);
            pu[3] = pk2(e1[2], e1[3]);
            o0 = mfma16(pa, vr[0], o0);
            o1 = mfma16(pa, vr[1], o1);
            o2 = mfma16(pa, vr[2], o2);
            o3 = mfma16(pa, vr[3], o3);
            __builtin_amdgcn_s_setprio(0);
        };

        int kt = lo;
        if (kt < hi) loadT(kt, krA, vrA);
        while (kt < hi) {
            if (kt + 1 < hi) loadT(kt + 1, krB, vrB);
            compT(kt, krA, vrA);
            ++kt;
            if (kt >= hi) break;
            if (kt + 1 < hi) loadT(kt + 1, krA, vrA);
            compT(kt, krB, vrB);
            ++kt;
        }

#pragma unroll
        for (int r = 0; r < 4; r++) {
            osum[wv][half][quad * 4 + r][l15]      = o0[r];
            osum[wv][half][quad * 4 + r][16 + l15] = o1[r];
            osum[wv][half][quad * 4 + r][32 + l15] = o2[r];
            osum[wv][half][quad * 4 + r][48 + l15] = o3[r];
        }
    }
    __syncthreads();

    const int half = tid >> 7;
    const int row = (tid >> 3) & 15;
    const int h0 = (tid & 7) * 8;
    const int s = half ? (127 - sA) : sA;
    float a[8];
#pragma unroll
    for (int i = 0; i < 8; i++) a[i] = 0.f;
#pragma unroll
    for (int w = 0; w < 4; w++)
#pragma unroll
        for (int i = 0; i < 8; i++) a[i] += osum[w][half][row][h0 + i];
    float* dst = &out[(size_t)(b * T_DIM + s * 16 + row) * H_DIM + h0];
    *(float4*)dst = make_float4(a[0], a[1], a[2], a[3]);
    *(float4*)(dst + 4) = make_float4(a[4], a[5], a[6], a[7]);
}

// ---------------------------------------------------------------------------
extern "C" void kernel_launch(void* const* d_in, const int* in_sizes, int n_in,
                              void* d_out, int out_size, void* d_ws, size_t ws_size,
                              hipStream_t stream) {
    const float* x  = (const float*)d_in[0];
    const float* Wk = (const float*)d_in[1];
    const float* Wq = (const float*)d_in[2];
    const float* Wv = (const float*)d_in[3];
    float* out = (float*)d_out;

    short* qbuf = (short*)d_ws;                       // 16384*64 bf16
    short* kbuf = qbuf + (size_t)16384 * 64;
    short* vtbuf = kbuf + (size_t)16384 * 64;         // [b][h][t]
    short* wtbuf = vtbuf + (size_t)16384 * 64;        // [3][64][1024]

    prep_kernel<<<48, 256, 0, stream>>>(Wq, Wk, Wv, wtbuf);
    proj_kernel<<<512, 256, 0, stream>>>(x, wtbuf, qbuf, kbuf, vtbuf);
    stats_kernel<<<512, 256, 0, stream>>>(qbuf, kbuf, vtbuf);
    out_kernel<<<512, 256, 0, stream>>>(qbuf, kbuf, vtbuf, out);
}